// Round 1
// baseline (10319.450 us; speedup 1.0000x reference)
//
#include <hip/hip_runtime.h>

#define H 51
#define G4 204           // 4*H
#define TSEQ 2048
#define BB 8             // batch elements per block
#define THREADS 256

__device__ __forceinline__ float sigf(float x) {
    // 1/(1+e^-x); saturates cleanly: e^inf -> inf -> rcp -> 0
    return __builtin_amdgcn_rcpf(1.0f + __expf(-x));
}
__device__ __forceinline__ float tanh_fast(float x) {
    // 1 - 2/(1+e^{2x}); x->+inf => 1, x->-inf => -1, no NaN
    return 1.0f - 2.0f * __builtin_amdgcn_rcpf(1.0f + __expf(2.0f * x));
}

__device__ __forceinline__ void cell_update(const float* __restrict__ Gs,
                                            int j, int b, float& c,
                                            float* __restrict__ hs) {
    float gi = Gs[(0 * H + j) * 8 + b];
    float gf = Gs[(1 * H + j) * 8 + b];
    float gg = Gs[(2 * H + j) * 8 + b];
    float go = Gs[(3 * H + j) * 8 + b];
    float si = sigf(gi), sf = sigf(gf), so = sigf(go);
    float tg = tanh_fast(gg);
    float cn = fmaf(sf, c, si * tg);
    c = cn;
    hs[j * 8 + b] = so * tanh_fast(cn);
}

__global__ __launch_bounds__(THREADS, 1)
void lstm_seq_kernel(const float* __restrict__ input,
                     const float* __restrict__ W_ih1, const float* __restrict__ W_hh1,
                     const float* __restrict__ b_ih1, const float* __restrict__ b_hh1,
                     const float* __restrict__ W_ih2, const float* __restrict__ W_hh2,
                     const float* __restrict__ b_ih2, const float* __restrict__ b_hh2,
                     const float* __restrict__ W_lin, const float* __restrict__ b_lin,
                     float* __restrict__ out)
{
    __shared__ float h1s[H * BB];        // h1[k][b]
    __shared__ float h2s[H * BB];        // h2[k][b]
    __shared__ float Gs[G4 * BB];        // gates[g][b] scratch (reused both layers)
    __shared__ float xss[64 * BB];       // x chunk [i][b]
    __shared__ float ybf[64 * BB];       // y buffer [i][b]
    __shared__ float wlin[H + 1];        // W_lin + b_lin

    const int tid  = threadIdx.x;
    const int wv   = tid >> 6;
    const int lane = tid & 63;
    const int b0   = blockIdx.x * BB;

    // ---- per-thread persistent weights in registers (lane<H owns gate row ga) ----
    float w1[H], w2i[H], w2h[H];
    float wx = 0.f, bias1 = 0.f, bias2 = 0.f;
    const int ga = wv * H + lane;
    if (lane < H) {
#pragma unroll
        for (int k = 0; k < H; ++k) {
            w1[k]  = W_hh1[ga * H + k];
            w2i[k] = W_ih2[ga * H + k];
            w2h[k] = W_hh2[ga * H + k];
        }
        wx    = W_ih1[ga];
        bias1 = b_ih1[ga] + b_hh1[ga];
        bias2 = b_ih2[ga] + b_hh2[ga];
    }
    if (tid < H)  wlin[tid] = W_lin[tid];
    if (tid == H) wlin[H]   = b_lin[0];

    for (int i = tid; i < H * BB; i += THREADS) { h1s[i] = 0.f; h2s[i] = 0.f; }
    float c1a = 0.f, c1b = 0.f, c2a = 0.f, c2b = 0.f;
    const int j0 = tid >> 3;   // cell unit (item 0); item 1 = j0+32
    const int bb = tid & 7;    // batch within block
    __syncthreads();

#pragma unroll 1
    for (int t = 0; t < TSEQ; ++t) {
        if ((t & 63) == 0) {
            // coalesced x chunk load: xss[i][b] = input[(b0+b)*T + t + i]
#pragma unroll
            for (int r = 0; r < 2; ++r) {
                int b = r * 4 + (tid >> 6);
                int i = tid & 63;
                xss[i * 8 + b] = input[(size_t)(b0 + b) * TSEQ + t + i];
            }
            __syncthreads();
        }

        // ---------------- matmul 1: gates1 = bias1 + wx*x + W_hh1 . h1 ----------------
        if (lane < H) {
            const float4 xA = *(const float4*)&xss[(t & 63) * 8];
            const float4 xB = *(const float4*)&xss[(t & 63) * 8 + 4];
            float a0 = fmaf(wx, xA.x, bias1), a1 = fmaf(wx, xA.y, bias1);
            float a2 = fmaf(wx, xA.z, bias1), a3 = fmaf(wx, xA.w, bias1);
            float a4 = fmaf(wx, xB.x, bias1), a5 = fmaf(wx, xB.y, bias1);
            float a6 = fmaf(wx, xB.z, bias1), a7 = fmaf(wx, xB.w, bias1);
#pragma unroll
            for (int k = 0; k < H; ++k) {
                const float4 hA = *(const float4*)&h1s[k * 8];
                const float4 hB = *(const float4*)&h1s[k * 8 + 4];
                const float w = w1[k];
                a0 = fmaf(w, hA.x, a0); a1 = fmaf(w, hA.y, a1);
                a2 = fmaf(w, hA.z, a2); a3 = fmaf(w, hA.w, a3);
                a4 = fmaf(w, hB.x, a4); a5 = fmaf(w, hB.y, a5);
                a6 = fmaf(w, hB.z, a6); a7 = fmaf(w, hB.w, a7);
            }
            *(float4*)&Gs[ga * 8]     = make_float4(a0, a1, a2, a3);
            *(float4*)&Gs[ga * 8 + 4] = make_float4(a4, a5, a6, a7);
        }
        __syncthreads();

        // ---------------- elementwise 1 (updates c1 regs, h1s in LDS) ----------------
        cell_update(Gs, j0, bb, c1a, h1s);
        if (tid < 152) cell_update(Gs, j0 + 32, bb, c1b, h1s);
        __syncthreads();

        // ---------------- matmul 2: gates2 = bias2 + W_ih2 . h1new + W_hh2 . h2 -------
        if (lane < H) {
            float a0 = bias2, a1 = bias2, a2 = bias2, a3 = bias2;
            float a4 = bias2, a5 = bias2, a6 = bias2, a7 = bias2;
#pragma unroll
            for (int k = 0; k < H; ++k) {
                const float4 hA = *(const float4*)&h1s[k * 8];
                const float4 hB = *(const float4*)&h1s[k * 8 + 4];
                const float w = w2i[k];
                a0 = fmaf(w, hA.x, a0); a1 = fmaf(w, hA.y, a1);
                a2 = fmaf(w, hA.z, a2); a3 = fmaf(w, hA.w, a3);
                a4 = fmaf(w, hB.x, a4); a5 = fmaf(w, hB.y, a5);
                a6 = fmaf(w, hB.z, a6); a7 = fmaf(w, hB.w, a7);
            }
#pragma unroll
            for (int k = 0; k < H; ++k) {
                const float4 hA = *(const float4*)&h2s[k * 8];
                const float4 hB = *(const float4*)&h2s[k * 8 + 4];
                const float w = w2h[k];
                a0 = fmaf(w, hA.x, a0); a1 = fmaf(w, hA.y, a1);
                a2 = fmaf(w, hA.z, a2); a3 = fmaf(w, hA.w, a3);
                a4 = fmaf(w, hB.x, a4); a5 = fmaf(w, hB.y, a5);
                a6 = fmaf(w, hB.z, a6); a7 = fmaf(w, hB.w, a7);
            }
            *(float4*)&Gs[ga * 8]     = make_float4(a0, a1, a2, a3);
            *(float4*)&Gs[ga * 8 + 4] = make_float4(a4, a5, a6, a7);
        }
        __syncthreads();

        // ---------------- elementwise 2 (updates c2 regs, h2s in LDS) ----------------
        cell_update(Gs, j0, bb, c2a, h2s);
        if (tid < 152) cell_update(Gs, j0 + 32, bb, c2b, h2s);
        __syncthreads();

        // ---------------- y = W_lin . h2new + b_lin (wave 0 only) --------------------
        if (wv == 0) {
            const int b = lane >> 3, ko = lane & 7;
            float acc = 0.f;
            for (int k = ko; k < H; k += 8)
                acc = fmaf(wlin[k], h2s[k * 8 + b], acc);
            acc += __shfl_xor(acc, 1, 64);
            acc += __shfl_xor(acc, 2, 64);
            acc += __shfl_xor(acc, 4, 64);
            if (ko == 0) ybf[(t & 63) * 8 + b] = acc + wlin[H];
        }

        if ((t & 63) == 63) {
            __syncthreads();   // wave0's ybf writes visible to all
#pragma unroll
            for (int r = 0; r < 2; ++r) {
                int b = r * 4 + (tid >> 6);
                int i = tid & 63;
                out[(size_t)(b0 + b) * TSEQ + (t - 63) + i] = ybf[i * 8 + b];
            }
        }
    }
}

extern "C" void kernel_launch(void* const* d_in, const int* in_sizes, int n_in,
                              void* d_out, int out_size, void* d_ws, size_t ws_size,
                              hipStream_t stream) {
    const float* input = (const float*)d_in[0];
    const float* W_ih1 = (const float*)d_in[1];
    const float* W_hh1 = (const float*)d_in[2];
    const float* b_ih1 = (const float*)d_in[3];
    const float* b_hh1 = (const float*)d_in[4];
    const float* W_ih2 = (const float*)d_in[5];
    const float* W_hh2 = (const float*)d_in[6];
    const float* b_ih2 = (const float*)d_in[7];
    const float* b_hh2 = (const float*)d_in[8];
    const float* W_lin = (const float*)d_in[9];
    const float* b_lin = (const float*)d_in[10];

    lstm_seq_kernel<<<dim3(2048 / BB / 1), dim3(THREADS), 0, stream>>>(
        input, W_ih1, W_hh1, b_ih1, b_hh1,
        W_ih2, W_hh2, b_ih2, b_hh2, W_lin, b_lin,
        (float*)d_out);
}

// Round 2
// 4307.254 us; speedup vs baseline: 2.3958x; 2.3958x over previous
//
#include <hip/hip_runtime.h>

#define H 51
#define TSEQ 2048
#define BB 8             // real batch elements per block (MFMA N=16, cols 8..15 are zero-pad)
#define THREADS 256

typedef __attribute__((ext_vector_type(8))) short short8;   // 8 bf16 = 4 VGPRs (MFMA A/B frag)
typedef __attribute__((ext_vector_type(4))) float float4v;  // MFMA C/D frag

__device__ __forceinline__ float sigf(float x) {
    return __builtin_amdgcn_rcpf(1.0f + __expf(-x));
}
__device__ __forceinline__ float tanh_fast(float x) {
    return 1.0f - 2.0f * __builtin_amdgcn_rcpf(1.0f + __expf(2.0f * x));
}
__device__ __forceinline__ unsigned short bf16_rne(float x) {
    unsigned u = __float_as_uint(x);
    u += 0x7FFF + ((u >> 16) & 1);
    return (unsigned short)(u >> 16);
}
__device__ __forceinline__ float bf16f(unsigned short h) {
    return __uint_as_float(((unsigned)h) << 16);
}

// A-matrix row order is REPACKED as [i_j, f_j, g_j, o_j] per cell j, so C/D row
// (quad*4+reg) = cell 4*tile+quad, gate reg -> elementwise is fully in-register.
__global__ __launch_bounds__(THREADS, 1)
void lstm_mfma_kernel(const float* __restrict__ input,
                      const float* __restrict__ W_ih1, const float* __restrict__ W_hh1,
                      const float* __restrict__ b_ih1, const float* __restrict__ b_hh1,
                      const float* __restrict__ W_ih2, const float* __restrict__ W_hh2,
                      const float* __restrict__ b_ih2, const float* __restrict__ b_hh2,
                      const float* __restrict__ W_lin, const float* __restrict__ b_lin,
                      float* __restrict__ out)
{
    // frag-linear bf16 h storage: [plane hi/lo][kstep][fraglane] -> 8 consecutive k
    __shared__ short8 hb1[2][2][64];
    __shared__ short8 hb2[2][2][64];
    __shared__ float  h2f[H * BB];     // fp32 h2 for the y-projection
    __shared__ float  xss[64 * BB];    // x chunk
    __shared__ float  ybf[64 * BB];    // y chunk
    __shared__ float  wlin[H + 1];

    const int tid  = threadIdx.x;
    const int wv   = tid >> 6;
    const int lane = tid & 63;
    const int n    = lane & 15;        // MFMA col (batch); n>=8 is zero-pad
    const int qd   = lane >> 4;        // quad
    const int b0   = blockIdx.x * BB;

    // ---- zero h-state LDS (cols 8..15 and k-pad stay zero forever) ----
    {
        short8 z = {0,0,0,0,0,0,0,0};
        (&hb1[0][0][0])[tid] = z;      // 2*2*64 == 256 == THREADS
        (&hb2[0][0][0])[tid] = z;
    }
    if (tid < H)  wlin[tid] = W_lin[tid];
    if (tid == H) wlin[H]   = b_lin[0];

    // ---- pack weights into persistent A-fragments (split bf16 hi/lo) ----
    // A layout: row m = lane&15 (within tile), k = quad*8 + j
    short8 wa1h[4][2], wa1l[4][2];     // layer1: W_hh1, K=64 (2 ksteps)
    short8 wa2h[4][4], wa2l[4][4];     // layer2: [s<2]=W_ih2 (k=h1), [s>=2]=W_hh2 (k=h2)
#pragma unroll
    for (int i = 0; i < 4; ++i) {
        const int tile = wv * 4 + i;                 // tiles 13..15 are dummy (zero)
        const int arow = tile * 16 + (lane & 15);
        const int cell = arow >> 2, gate = arow & 3;
        const int orow = gate * H + cell;            // original PyTorch row
        const bool rok = (arow < 4 * H);
#pragma unroll
        for (int s = 0; s < 2; ++s) {
#pragma unroll
            for (int j = 0; j < 8; ++j) {
                int kk = s * 32 + qd * 8 + j;
                float w = (rok && kk < H) ? W_hh1[orow * H + kk] : 0.f;
                unsigned short hi = bf16_rne(w);
                wa1h[i][s][j] = (short)hi;
                wa1l[i][s][j] = (short)bf16_rne(w - bf16f(hi));
            }
        }
#pragma unroll
        for (int s = 0; s < 4; ++s) {
#pragma unroll
            for (int j = 0; j < 8; ++j) {
                int kk = s * 32 + qd * 8 + j;
                float w = 0.f;
                if (rok) {
                    if (kk < H)                          w = W_ih2[orow * H + kk];
                    else if (kk >= 64 && kk < 64 + H)    w = W_hh2[orow * H + (kk - 64)];
                }
                unsigned short hi = bf16_rne(w);
                wa2h[i][s][j] = (short)hi;
                wa2l[i][s][j] = (short)bf16_rne(w - bf16f(hi));
            }
        }
    }

    // ---- per-lane elementwise constants (cell j = 4*tile + quad) ----
    float4v bias1v[4], wih1v[4], bias2v[4];
    int  cellj[4];
    bool cok[4];
#pragma unroll
    for (int i = 0; i < 4; ++i) {
        const int tile = wv * 4 + i;
        const int j = tile * 4 + qd;
        cellj[i] = j;
        cok[i]   = (j < H);
#pragma unroll
        for (int r = 0; r < 4; ++r) {
            const int orow = r * H + j;
            bias1v[i][r] = cok[i] ? (b_ih1[orow] + b_hh1[orow]) : 0.f;
            wih1v[i][r]  = cok[i] ? W_ih1[orow] : 0.f;
            bias2v[i][r] = cok[i] ? (b_ih2[orow] + b_hh2[orow]) : 0.f;
        }
    }

    // persistent h1 B-frags (regs): loaded by mm2(t), reused by mm1(t+1)
    short8 f1h[2], f1l[2];
    {
        short8 z = {0,0,0,0,0,0,0,0};
        f1h[0] = z; f1h[1] = z; f1l[0] = z; f1l[1] = z;
    }
    float c1[4] = {0.f, 0.f, 0.f, 0.f};
    float c2[4] = {0.f, 0.f, 0.f, 0.f};

    __syncthreads();

#pragma unroll 1
    for (int t = 0; t < TSEQ; ++t) {
        if ((t & 63) == 0) {
#pragma unroll
            for (int r = 0; r < 2; ++r) {
                int b = r * 4 + (tid >> 6);
                int i = tid & 63;
                xss[i * 8 + b] = input[(size_t)(b0 + b) * TSEQ + t + i];
            }
            __syncthreads();
        }

        const float xb = (n < 8) ? xss[(t & 63) * 8 + n] : 0.f;

        // ================= layer 1: gates = bias + Wih1*x + Whh1·h1 =================
        float4v acc[4];
#pragma unroll
        for (int i = 0; i < 4; ++i) {
            acc[i] = bias1v[i];
#pragma unroll
            for (int r = 0; r < 4; ++r) acc[i][r] = fmaf(wih1v[i][r], xb, acc[i][r]);
        }
#pragma unroll
        for (int s = 0; s < 2; ++s) {
#pragma unroll
            for (int i = 0; i < 4; ++i) {
                acc[i] = __builtin_amdgcn_mfma_f32_16x16x32_bf16(wa1h[i][s], f1h[s], acc[i], 0, 0, 0);
                acc[i] = __builtin_amdgcn_mfma_f32_16x16x32_bf16(wa1h[i][s], f1l[s], acc[i], 0, 0, 0);
                acc[i] = __builtin_amdgcn_mfma_f32_16x16x32_bf16(wa1l[i][s], f1h[s], acc[i], 0, 0, 0);
            }
        }

        // elementwise 1 (in-register gates) -> write h1_new hi/lo to LDS
#pragma unroll
        for (int i = 0; i < 4; ++i) {
            float cn = fmaf(sigf(acc[i][1]), c1[i], sigf(acc[i][0]) * tanh_fast(acc[i][2]));
            c1[i] = cn;
            float h = sigf(acc[i][3]) * tanh_fast(cn);
            if (cok[i] && n < 8) {
                int j = cellj[i];
                int s = j >> 5, q = (j & 31) >> 3, j7 = j & 7;
                unsigned short hi = bf16_rne(h);
                ((short*)&hb1[0][s][q * 16 + n])[j7] = (short)hi;
                ((short*)&hb1[1][s][q * 16 + n])[j7] = (short)bf16_rne(h - bf16f(hi));
            }
        }
        __syncthreads();   // B_a: h1_new visible

        // B-frag loads: h1_new (reused next step by mm1) + h2_old
        short8 f2h[2], f2l[2];
#pragma unroll
        for (int s = 0; s < 2; ++s) {
            f1h[s] = hb1[0][s][lane];
            f1l[s] = hb1[1][s][lane];
            f2h[s] = hb2[0][s][lane];
            f2l[s] = hb2[1][s][lane];
        }
        __syncthreads();   // B_b: all loads drained before hb2 is overwritten

        // ================= layer 2: gates = bias2 + Wih2·h1_new + Whh2·h2 =================
#pragma unroll
        for (int i = 0; i < 4; ++i) acc[i] = bias2v[i];
#pragma unroll
        for (int s = 0; s < 2; ++s) {
#pragma unroll
            for (int i = 0; i < 4; ++i) {
                acc[i] = __builtin_amdgcn_mfma_f32_16x16x32_bf16(wa2h[i][s], f1h[s], acc[i], 0, 0, 0);
                acc[i] = __builtin_amdgcn_mfma_f32_16x16x32_bf16(wa2h[i][s], f1l[s], acc[i], 0, 0, 0);
                acc[i] = __builtin_amdgcn_mfma_f32_16x16x32_bf16(wa2l[i][s], f1h[s], acc[i], 0, 0, 0);
            }
        }
#pragma unroll
        for (int s = 0; s < 2; ++s) {
#pragma unroll
            for (int i = 0; i < 4; ++i) {
                acc[i] = __builtin_amdgcn_mfma_f32_16x16x32_bf16(wa2h[i][s + 2], f2h[s], acc[i], 0, 0, 0);
                acc[i] = __builtin_amdgcn_mfma_f32_16x16x32_bf16(wa2h[i][s + 2], f2l[s], acc[i], 0, 0, 0);
                acc[i] = __builtin_amdgcn_mfma_f32_16x16x32_bf16(wa2l[i][s + 2], f2h[s], acc[i], 0, 0, 0);
            }
        }

        // elementwise 2 -> write h2_new hi/lo + fp32 copy for y
#pragma unroll
        for (int i = 0; i < 4; ++i) {
            float cn = fmaf(sigf(acc[i][1]), c2[i], sigf(acc[i][0]) * tanh_fast(acc[i][2]));
            c2[i] = cn;
            float h = sigf(acc[i][3]) * tanh_fast(cn);
            if (cok[i] && n < 8) {
                int j = cellj[i];
                int s = j >> 5, q = (j & 31) >> 3, j7 = j & 7;
                unsigned short hi = bf16_rne(h);
                ((short*)&hb2[0][s][q * 16 + n])[j7] = (short)hi;
                ((short*)&hb2[1][s][q * 16 + n])[j7] = (short)bf16_rne(h - bf16f(hi));
                h2f[j * 8 + n] = h;
            }
        }
        __syncthreads();   // B_c: h2_new / h2f visible

        // ---- y = W_lin · h2_new + b_lin (wave 0; others run ahead to mm1(t+1)) ----
        if (wv == 0) {
            const int b = lane & 7, kg = lane >> 3;
            float a = 0.f;
#pragma unroll
            for (int it = 0; it < 7; ++it) {
                int j = kg + it * 8;
                if (j < H) a = fmaf(wlin[j], h2f[j * 8 + b], a);
            }
            a += __shfl_xor(a, 8, 64);
            a += __shfl_xor(a, 16, 64);
            a += __shfl_xor(a, 32, 64);
            if (kg == 0) ybf[(t & 63) * 8 + b] = a + wlin[H];
        }

        if ((t & 63) == 63) {
            __syncthreads();   // ybf complete
#pragma unroll
            for (int r = 0; r < 2; ++r) {
                int b = r * 4 + (tid >> 6);
                int i = tid & 63;
                out[(size_t)(b0 + b) * TSEQ + (t - 63) + i] = ybf[i * 8 + b];
            }
        }
    }
}

extern "C" void kernel_launch(void* const* d_in, const int* in_sizes, int n_in,
                              void* d_out, int out_size, void* d_ws, size_t ws_size,
                              hipStream_t stream) {
    const float* input = (const float*)d_in[0];
    const float* W_ih1 = (const float*)d_in[1];
    const float* W_hh1 = (const float*)d_in[2];
    const float* b_ih1 = (const float*)d_in[3];
    const float* b_hh1 = (const float*)d_in[4];
    const float* W_ih2 = (const float*)d_in[5];
    const float* W_hh2 = (const float*)d_in[6];
    const float* b_ih2 = (const float*)d_in[7];
    const float* b_hh2 = (const float*)d_in[8];
    const float* W_lin = (const float*)d_in[9];
    const float* b_lin = (const float*)d_in[10];

    lstm_mfma_kernel<<<dim3(2048 / BB), dim3(THREADS), 0, stream>>>(
        input, W_ih1, W_hh1, b_ih1, b_hh1,
        W_ih2, W_hh2, b_ih2, b_hh2, W_lin, b_lin,
        (float*)d_out);
}

// Round 3
// 3929.474 us; speedup vs baseline: 2.6262x; 1.0961x over previous
//
#include <hip/hip_runtime.h>

#define H 51
#define TSEQ 2048
#define BB 8             // real batch per block (MFMA N=16, cols 8..15 zero-pad)
#define THREADS 256

typedef __attribute__((ext_vector_type(8))) short short8;   // 8 bf16 (MFMA A/B frag)
typedef __attribute__((ext_vector_type(4))) float float4v;  // MFMA C/D frag

__device__ __forceinline__ float sigf(float x) {
    return __builtin_amdgcn_rcpf(1.0f + __expf(-x));
}
__device__ __forceinline__ float tanh_fast(float x) {
    return 1.0f - 2.0f * __builtin_amdgcn_rcpf(1.0f + __expf(2.0f * x));
}
__device__ __forceinline__ unsigned short bf16_rne(float x) {
    unsigned u = __float_as_uint(x);
    u += 0x7FFF + ((u >> 16) & 1);
    return (unsigned short)(u >> 16);
}
__device__ __forceinline__ float bf16f(unsigned short h) {
    return __uint_as_float(((unsigned)h) << 16);
}

// A rows repacked [i_j,f_j,g_j,o_j] per cell j -> C/D reg r == gate r, cell = tile*4+quad.
// Tile map: slot i of wave wv owns tile (wv + 4*i); tiles 13..15 are dummy (zero weights).
// Ping-pong h buffers by t parity -> single barrier per step.
__global__ __launch_bounds__(THREADS, 1)
void lstm_mfma_kernel(const float* __restrict__ input,
                      const float* __restrict__ W_ih1, const float* __restrict__ W_hh1,
                      const float* __restrict__ b_ih1, const float* __restrict__ b_hh1,
                      const float* __restrict__ W_ih2, const float* __restrict__ W_hh2,
                      const float* __restrict__ b_ih2, const float* __restrict__ b_hh2,
                      const float* __restrict__ W_lin, const float* __restrict__ b_lin,
                      float* __restrict__ out)
{
    // [parity][plane hi/lo][kstep][fraglane]
    __shared__ short8 hb1[2][2][2][64];
    __shared__ short8 hb2[2][2][2][64];
    __shared__ float  h2f[2][H * BB];   // fp32 h2 for y (ping-pong)
    __shared__ float  xss[64 * BB];     // x chunk [i][b]
    __shared__ float  ybf[BB][64];      // y buffer [b][i]  (wave3-private)
    __shared__ float  wlin[H + 1];

    const int tid  = threadIdx.x;
    const int wv   = tid >> 6;
    const int lane = tid & 63;
    const int n    = lane & 15;         // MFMA col (batch); n>=8 pad
    const int qd   = lane >> 4;         // quad
    const int b0   = blockIdx.x * BB;

    {   // zero both parities of h-state
        short8 z = {0,0,0,0,0,0,0,0};
        short8* p1 = &hb1[0][0][0][0];
        short8* p2 = &hb2[0][0][0][0];
        p1[tid] = z; p1[tid + 256] = z;
        p2[tid] = z; p2[tid + 256] = z;
    }
    if (tid < H)  wlin[tid] = W_lin[tid];
    if (tid == H) wlin[H]   = b_lin[0];

    // ---- persistent A-fragments, split bf16 hi/lo ----
    short8 wa1h[4][2], wa1l[4][2];      // W_hh1 (K=64)
    short8 wa2h[4][4], wa2l[4][4];      // s<2: W_ih2 (k=h1) ; s>=2: W_hh2 (k=h2)
    bool tok[4];
#pragma unroll
    for (int i = 0; i < 4; ++i) {
        const int tile = wv + 4 * i;
        tok[i] = (tile * 16 < 4 * H);
        const int arow = tile * 16 + (lane & 15);
        const int cell = arow >> 2, gate = arow & 3;
        const int orow = gate * H + cell;
        const bool rok = (arow < 4 * H);
#pragma unroll
        for (int s = 0; s < 2; ++s) {
#pragma unroll
            for (int j = 0; j < 8; ++j) {
                int kk = s * 32 + qd * 8 + j;
                float w = (rok && kk < H) ? W_hh1[orow * H + kk] : 0.f;
                unsigned short hi = bf16_rne(w);
                wa1h[i][s][j] = (short)hi;
                wa1l[i][s][j] = (short)bf16_rne(w - bf16f(hi));
            }
        }
#pragma unroll
        for (int s = 0; s < 4; ++s) {
#pragma unroll
            for (int j = 0; j < 8; ++j) {
                int kk = s * 32 + qd * 8 + j;
                float w = 0.f;
                if (rok) {
                    if (kk < H)                       w = W_ih2[orow * H + kk];
                    else if (kk >= 64 && kk < 64 + H) w = W_hh2[orow * H + (kk - 64)];
                }
                unsigned short hi = bf16_rne(w);
                wa2h[i][s][j] = (short)hi;
                wa2l[i][s][j] = (short)bf16_rne(w - bf16f(hi));
            }
        }
    }

    // ---- per-lane elementwise constants ----
    float4v bias1v[4], wih1v[4], bias2v[4];
    int  cellj[4]; bool cok[4];
#pragma unroll
    for (int i = 0; i < 4; ++i) {
        const int tile = wv + 4 * i;
        const int j = tile * 4 + qd;
        cellj[i] = j; cok[i] = (j < H);
#pragma unroll
        for (int r = 0; r < 4; ++r) {
            const int orow = r * H + j;
            bias1v[i][r] = cok[i] ? (b_ih1[orow] + b_hh1[orow]) : 0.f;
            wih1v[i][r]  = cok[i] ? W_ih1[orow] : 0.f;
            bias2v[i][r] = cok[i] ? (b_ih2[orow] + b_hh2[orow]) : 0.f;
        }
    }

    short8 f1h[2], f1l[2], f2h[2], f2l[2];
    {
        short8 z = {0,0,0,0,0,0,0,0};
        f1h[0]=z; f1h[1]=z; f1l[0]=z; f1l[1]=z;
        f2h[0]=z; f2h[1]=z; f2l[0]=z; f2l[1]=z;
    }
    float c1[4] = {0.f,0.f,0.f,0.f};
    float c2[4] = {0.f,0.f,0.f,0.f};

    __syncthreads();

#pragma unroll 1
    for (int t = 0; t < TSEQ; ++t) {
        const int p = t & 1;

        if ((t & 63) == 0) {
#pragma unroll
            for (int r = 0; r < 2; ++r) {
                int b = r * 4 + wv;
                xss[lane * 8 + b] = input[(size_t)(b0 + b) * TSEQ + t + lane];
            }
            __syncthreads();
        }
        const float xb = (n < 8) ? xss[(t & 63) * 8 + n] : 0.f;

        // ---------- layer 1: acc1 = bias1 + Wih1*x + Whh1·h1(t-1) ----------
        float4v acc1[4];
#pragma unroll
        for (int i = 0; i < 4; ++i)
#pragma unroll
            for (int r = 0; r < 4; ++r)
                acc1[i][r] = fmaf(wih1v[i][r], xb, bias1v[i][r]);
#pragma unroll
        for (int s = 0; s < 2; ++s)
#pragma unroll
            for (int i = 0; i < 4; ++i) {
                acc1[i] = __builtin_amdgcn_mfma_f32_16x16x32_bf16(wa1h[i][s], f1h[s], acc1[i], 0, 0, 0);
                acc1[i] = __builtin_amdgcn_mfma_f32_16x16x32_bf16(wa1h[i][s], f1l[s], acc1[i], 0, 0, 0);
                acc1[i] = __builtin_amdgcn_mfma_f32_16x16x32_bf16(wa1l[i][s], f1h[s], acc1[i], 0, 0, 0);
            }

        // ---------- elementwise 1 -> hb1[p] ----------
#pragma unroll
        for (int i = 0; i < 4; ++i) if (tok[i]) {
            float cn = fmaf(sigf(acc1[i][1]), c1[i], sigf(acc1[i][0]) * tanh_fast(acc1[i][2]));
            c1[i] = cn;
            float h = sigf(acc1[i][3]) * tanh_fast(cn);
            if (cok[i] && n < 8) {
                int j = cellj[i];
                int s = j >> 5, q = (j & 31) >> 3, j7 = j & 7;
                unsigned short hi = bf16_rne(h);
                ((short*)&hb1[p][0][s][q * 16 + n])[j7] = (short)hi;
                ((short*)&hb1[p][1][s][q * 16 + n])[j7] = (short)bf16_rne(h - bf16f(hi));
            }
        }

        __syncthreads();   // THE barrier: publishes h1(t); h2(t-1) already published last step

        // ---------- frag loads: h1(t) and h2(t-1) ----------
#pragma unroll
        for (int s = 0; s < 2; ++s) {
            f1h[s] = hb1[p][0][s][lane];
            f1l[s] = hb1[p][1][s][lane];
            f2h[s] = hb2[p ^ 1][0][s][lane];
            f2l[s] = hb2[p ^ 1][1][s][lane];
        }

        // ---------- y(t-1) + flush: wave3 only, off critical path ----------
        if (wv == 3 && t > 0) {
            const int b = lane & 7, kg = lane >> 3;
            float a = 0.f;
#pragma unroll
            for (int it = 0; it < 7; ++it) {
                int j = kg + it * 8;
                if (j < H) a = fmaf(wlin[j], h2f[p ^ 1][j * 8 + b], a);
            }
            a += __shfl_xor(a, 8, 64);
            a += __shfl_xor(a, 16, 64);
            a += __shfl_xor(a, 32, 64);
            if (kg == 0) ybf[b][(t - 1) & 63] = a + wlin[H];
            if ((t & 63) == 0) {        // flush chunk [t-64, t-1]
                int tb = t - 64;
#pragma unroll
                for (int r = 0; r < 8; ++r)
                    out[(size_t)(b0 + r) * TSEQ + tb + lane] = ybf[r][lane];
            }
        }

        // ---------- layer 2: acc2 = bias2 + Wih2·h1(t) + Whh2·h2(t-1) ----------
        float4v acc2[4];
#pragma unroll
        for (int i = 0; i < 4; ++i) acc2[i] = bias2v[i];
#pragma unroll
        for (int s = 0; s < 2; ++s)
#pragma unroll
            for (int i = 0; i < 4; ++i) {
                acc2[i] = __builtin_amdgcn_mfma_f32_16x16x32_bf16(wa2h[i][s], f1h[s], acc2[i], 0, 0, 0);
                acc2[i] = __builtin_amdgcn_mfma_f32_16x16x32_bf16(wa2h[i][s], f1l[s], acc2[i], 0, 0, 0);
                acc2[i] = __builtin_amdgcn_mfma_f32_16x16x32_bf16(wa2l[i][s], f1h[s], acc2[i], 0, 0, 0);
            }
#pragma unroll
        for (int s = 0; s < 2; ++s)
#pragma unroll
            for (int i = 0; i < 4; ++i) {
                acc2[i] = __builtin_amdgcn_mfma_f32_16x16x32_bf16(wa2h[i][s + 2], f2h[s], acc2[i], 0, 0, 0);
                acc2[i] = __builtin_amdgcn_mfma_f32_16x16x32_bf16(wa2h[i][s + 2], f2l[s], acc2[i], 0, 0, 0);
                acc2[i] = __builtin_amdgcn_mfma_f32_16x16x32_bf16(wa2l[i][s + 2], f2h[s], acc2[i], 0, 0, 0);
            }

        // ---------- elementwise 2 -> hb2[p], h2f[p] ----------
#pragma unroll
        for (int i = 0; i < 4; ++i) if (tok[i]) {
            float cn = fmaf(sigf(acc2[i][1]), c2[i], sigf(acc2[i][0]) * tanh_fast(acc2[i][2]));
            c2[i] = cn;
            float h = sigf(acc2[i][3]) * tanh_fast(cn);
            if (cok[i] && n < 8) {
                int j = cellj[i];
                int s = j >> 5, q = (j & 31) >> 3, j7 = j & 7;
                unsigned short hi = bf16_rne(h);
                ((short*)&hb2[p][0][s][q * 16 + n])[j7] = (short)hi;
                ((short*)&hb2[p][1][s][q * 16 + n])[j7] = (short)bf16_rne(h - bf16f(hi));
                h2f[p][j * 8 + n] = h;
            }
        }
        // no trailing barrier: next iteration's barrier covers publication
    }

    // ---------- epilogue: y(2047) + final chunk flush ----------
    __syncthreads();   // h2f[1] (written at t=2047) visible
    if (wv == 3) {
        const int b = lane & 7, kg = lane >> 3;
        float a = 0.f;
#pragma unroll
        for (int it = 0; it < 7; ++it) {
            int j = kg + it * 8;
            if (j < H) a = fmaf(wlin[j], h2f[1][j * 8 + b], a);
        }
        a += __shfl_xor(a, 8, 64);
        a += __shfl_xor(a, 16, 64);
        a += __shfl_xor(a, 32, 64);
        if (kg == 0) ybf[b][63] = a + wlin[H];
#pragma unroll
        for (int r = 0; r < 8; ++r)
            out[(size_t)(b0 + r) * TSEQ + 1984 + lane] = ybf[r][lane];
    }
}

extern "C" void kernel_launch(void* const* d_in, const int* in_sizes, int n_in,
                              void* d_out, int out_size, void* d_ws, size_t ws_size,
                              hipStream_t stream) {
    const float* input = (const float*)d_in[0];
    const float* W_ih1 = (const float*)d_in[1];
    const float* W_hh1 = (const float*)d_in[2];
    const float* b_ih1 = (const float*)d_in[3];
    const float* b_hh1 = (const float*)d_in[4];
    const float* W_ih2 = (const float*)d_in[5];
    const float* W_hh2 = (const float*)d_in[6];
    const float* b_ih2 = (const float*)d_in[7];
    const float* b_hh2 = (const float*)d_in[8];
    const float* W_lin = (const float*)d_in[9];
    const float* b_lin = (const float*)d_in[10];

    lstm_mfma_kernel<<<dim3(2048 / BB), dim3(THREADS), 0, stream>>>(
        input, W_ih1, W_hh1, b_ih1, b_hh1,
        W_ih2, W_hh2, b_ih2, b_hh2, W_lin, b_lin,
        (float*)d_out);
}

// Round 4
// 2573.053 us; speedup vs baseline: 4.0106x; 1.5272x over previous
//
#include <hip/hip_runtime.h>

#define H 51
#define TSEQ 2048
#define BB 16            // batch per block — fills all 16 MFMA columns
#define THREADS 512      // 8 waves, 2 tile-slots each, 2 waves/SIMD

typedef __attribute__((ext_vector_type(8))) short short8;   // 8 bf16 (MFMA A/B frag)
typedef __attribute__((ext_vector_type(4))) float float4v;  // MFMA C/D frag

#define LOG2E    1.44269504f
#define TWOLOG2E 2.88539008f

// gate rows pre-scaled by log2e (i,f,o) / 2*log2e (g) -> raw v_exp, no mul
__device__ __forceinline__ float sig_pre(float u) {   // sigmoid(g), u = g*log2e
    return __builtin_amdgcn_rcpf(1.0f + __builtin_amdgcn_exp2f(-u));
}
__device__ __forceinline__ float tanh_pre(float u) {  // tanh(g),  u = g*2log2e
    return 1.0f - 2.0f * __builtin_amdgcn_rcpf(1.0f + __builtin_amdgcn_exp2f(u));
}
__device__ __forceinline__ unsigned short bf16_rne(float x) {
    unsigned u = __float_as_uint(x);
    u += 0x7FFF + ((u >> 16) & 1);
    return (unsigned short)(u >> 16);
}
__device__ __forceinline__ float bf16f(unsigned short h) {
    return __uint_as_float(((unsigned)h) << 16);
}

// A rows repacked [i_j,f_j,g_j,o_j] per cell j -> C/D reg r == gate r, cell = tile*4+quad.
// Tile map: slot i of wave wv owns tile (wv + 8*i); tiles 13..15 dummy (zero weights).
// Ping-pong h buffers by t parity -> one barrier per step. x chunk double-buffered.
__global__ __launch_bounds__(THREADS, 2)
void lstm_mfma_kernel(const float* __restrict__ input,
                      const float* __restrict__ W_ih1, const float* __restrict__ W_hh1,
                      const float* __restrict__ b_ih1, const float* __restrict__ b_hh1,
                      const float* __restrict__ W_ih2, const float* __restrict__ W_hh2,
                      const float* __restrict__ b_ih2, const float* __restrict__ b_hh2,
                      const float* __restrict__ W_lin, const float* __restrict__ b_lin,
                      float* __restrict__ out)
{
    // [parity][plane hi/lo][kstep][fraglane]
    __shared__ short8 hb1[2][2][2][64];
    __shared__ short8 hb2[2][2][2][64];
    __shared__ float  h2f[2][H * BB];     // fp32 h2 for y (ping-pong)
    __shared__ float  xss[2][64 * 17];    // x chunks, [i*17+b] (17: conflict-free)
    __shared__ float  ybf[BB][64];        // y buffer [b][i] (wave7-private)
    __shared__ float  wlin[H + 1];

    const int tid  = threadIdx.x;
    const int wv   = tid >> 6;            // 0..7
    const int lane = tid & 63;
    const int n    = lane & 15;           // MFMA col = batch (all 16 real)
    const int qd   = lane >> 4;           // quad
    const int b0   = blockIdx.x * BB;

    {   // zero both parities of h-state: 512 short8 per array == THREADS
        short8 z = {0,0,0,0,0,0,0,0};
        (&hb1[0][0][0][0])[tid] = z;
        (&hb2[0][0][0][0])[tid] = z;
    }
    if (tid < H)  wlin[tid] = W_lin[tid];
    if (tid == H) wlin[H]   = b_lin[0];

    // x chunk 0
#pragma unroll
    for (int r = 0; r < 2; ++r) {
        int b = wv + 8 * r;
        xss[0][lane * 17 + b] = input[(size_t)(b0 + b) * TSEQ + lane];
    }

    // ---- persistent A-fragments, split bf16 hi/lo, gate rows pre-scaled ----
    short8 wa1h[2][2], wa1l[2][2];        // W_hh1 (K=64)
    short8 wa2h[2][4], wa2l[2][4];        // s<2: W_ih2 (k=h1); s>=2: W_hh2 (k=h2)
    bool tok[2];
#pragma unroll
    for (int i = 0; i < 2; ++i) {
        const int tile = wv + 8 * i;
        tok[i] = (tile * 16 < 4 * H);
        const int arow = tile * 16 + (lane & 15);
        const int cell = arow >> 2, gate = arow & 3;
        const int orow = gate * H + cell;
        const float gsc = (gate == 2) ? TWOLOG2E : LOG2E;
        const bool rok = (arow < 4 * H);
#pragma unroll
        for (int s = 0; s < 2; ++s) {
#pragma unroll
            for (int j = 0; j < 8; ++j) {
                int kk = s * 32 + qd * 8 + j;
                float w = (rok && kk < H) ? gsc * W_hh1[orow * H + kk] : 0.f;
                unsigned short hi = bf16_rne(w);
                wa1h[i][s][j] = (short)hi;
                wa1l[i][s][j] = (short)bf16_rne(w - bf16f(hi));
            }
        }
#pragma unroll
        for (int s = 0; s < 4; ++s) {
#pragma unroll
            for (int j = 0; j < 8; ++j) {
                int kk = s * 32 + qd * 8 + j;
                float w = 0.f;
                if (rok) {
                    if (kk < H)                       w = gsc * W_ih2[orow * H + kk];
                    else if (kk >= 64 && kk < 64 + H) w = gsc * W_hh2[orow * H + (kk - 64)];
                }
                unsigned short hi = bf16_rne(w);
                wa2h[i][s][j] = (short)hi;
                wa2l[i][s][j] = (short)bf16_rne(w - bf16f(hi));
            }
        }
    }

    // ---- per-lane elementwise constants (cell j = tile*4 + quad), pre-scaled ----
    float4v bias1v[2], wih1v[2], bias2v[2];
    int  cellj[2]; bool cok[2];
#pragma unroll
    for (int i = 0; i < 2; ++i) {
        const int tile = wv + 8 * i;
        const int j = tile * 4 + qd;
        cellj[i] = j; cok[i] = (j < H);
#pragma unroll
        for (int r = 0; r < 4; ++r) {
            const int orow = r * H + j;
            const float gsc = (r == 2) ? TWOLOG2E : LOG2E;
            bias1v[i][r] = cok[i] ? gsc * (b_ih1[orow] + b_hh1[orow]) : 0.f;
            wih1v[i][r]  = cok[i] ? gsc * W_ih1[orow] : 0.f;
            bias2v[i][r] = cok[i] ? gsc * (b_ih2[orow] + b_hh2[orow]) : 0.f;
        }
    }

    short8 f1h[2], f1l[2], f2h[2], f2l[2];
    {
        short8 z = {0,0,0,0,0,0,0,0};
        f1h[0]=z; f1h[1]=z; f1l[0]=z; f1l[1]=z;
        f2h[0]=z; f2h[1]=z; f2l[0]=z; f2l[1]=z;
    }
    float c1[2] = {0.f,0.f};
    float c2[2] = {0.f,0.f};

    __syncthreads();

#pragma unroll 1
    for (int t = 0; t < TSEQ; ++t) {
        const int p  = t & 1;
        const int cp = (t >> 6) & 1;

        // mid-chunk prefetch of next x chunk (latency hidden across ~32 steps)
        if ((t & 63) == 32 && t + 32 < TSEQ) {
#pragma unroll
            for (int r = 0; r < 2; ++r) {
                int b = wv + 8 * r;
                xss[cp ^ 1][lane * 17 + b] = input[(size_t)(b0 + b) * TSEQ + (t + 32) + lane];
            }
        }
        const float xb = xss[cp][(t & 63) * 17 + n];

        // ---------- layer 1: acc1 = bias1 + Wih1*x + Whh1·h1(t-1) ----------
        float4v acc1[2];
#pragma unroll
        for (int i = 0; i < 2; ++i)
#pragma unroll
            for (int r = 0; r < 4; ++r)
                acc1[i][r] = fmaf(wih1v[i][r], xb, bias1v[i][r]);
#pragma unroll
        for (int s = 0; s < 2; ++s)
#pragma unroll
            for (int i = 0; i < 2; ++i) {
                acc1[i] = __builtin_amdgcn_mfma_f32_16x16x32_bf16(wa1h[i][s], f1h[s], acc1[i], 0, 0, 0);
                acc1[i] = __builtin_amdgcn_mfma_f32_16x16x32_bf16(wa1h[i][s], f1l[s], acc1[i], 0, 0, 0);
                acc1[i] = __builtin_amdgcn_mfma_f32_16x16x32_bf16(wa1l[i][s], f1h[s], acc1[i], 0, 0, 0);
            }

        // ---------- elementwise 1 -> hb1[p] ----------
#pragma unroll
        for (int i = 0; i < 2; ++i) if (tok[i]) {
            float cn = fmaf(sig_pre(acc1[i][1]), c1[i], sig_pre(acc1[i][0]) * tanh_pre(acc1[i][2]));
            c1[i] = cn;
            float h = sig_pre(acc1[i][3]) * tanh_pre(cn * TWOLOG2E);
            if (cok[i]) {
                int j = cellj[i];
                int s = j >> 5, q = (j & 31) >> 3, j7 = j & 7;
                unsigned short hi = bf16_rne(h);
                ((short*)&hb1[p][0][s][q * 16 + n])[j7] = (short)hi;
                ((short*)&hb1[p][1][s][q * 16 + n])[j7] = (short)bf16_rne(h - bf16f(hi));
            }
        }

        __syncthreads();   // THE barrier: publishes h1(t); h2(t-1)/h2f(t-1) from last step

        // ---------- frag loads: h1(t) and h2(t-1) ----------
#pragma unroll
        for (int s = 0; s < 2; ++s) {
            f1h[s] = hb1[p][0][s][lane];
            f1l[s] = hb1[p][1][s][lane];
            f2h[s] = hb2[p ^ 1][0][s][lane];
            f2l[s] = hb2[p ^ 1][1][s][lane];
        }

        // ---------- y(t-1) + flush: wave7 only (wave7 has 1 real tile) ----------
        if (wv == 7 && t > 0) {
            const int b = lane & 15, kg = lane >> 4;
            float a = 0.f;
#pragma unroll
            for (int it = 0; it < 13; ++it) {
                int j = kg + it * 4;
                if (j < H) a = fmaf(wlin[j], h2f[p ^ 1][j * 16 + b], a);
            }
            a += __shfl_xor(a, 16, 64);
            a += __shfl_xor(a, 32, 64);
            if (kg == 0) ybf[b][(t - 1) & 63] = a + wlin[H];
            if ((t & 63) == 0) {        // flush chunk [t-64, t-1]
                int tb = t - 64;
#pragma unroll
                for (int r = 0; r < BB; ++r)
                    out[(size_t)(b0 + r) * TSEQ + tb + lane] = ybf[r][lane];
            }
        }

        // ---------- layer 2: acc2 = bias2 + Wih2·h1(t) + Whh2·h2(t-1) ----------
        float4v acc2[2];
#pragma unroll
        for (int i = 0; i < 2; ++i) acc2[i] = bias2v[i];
#pragma unroll
        for (int s = 0; s < 2; ++s)
#pragma unroll
            for (int i = 0; i < 2; ++i) {
                acc2[i] = __builtin_amdgcn_mfma_f32_16x16x32_bf16(wa2h[i][s], f1h[s], acc2[i], 0, 0, 0);
                acc2[i] = __builtin_amdgcn_mfma_f32_16x16x32_bf16(wa2h[i][s], f1l[s], acc2[i], 0, 0, 0);
                acc2[i] = __builtin_amdgcn_mfma_f32_16x16x32_bf16(wa2l[i][s], f1h[s], acc2[i], 0, 0, 0);
            }
#pragma unroll
        for (int s = 0; s < 2; ++s)
#pragma unroll
            for (int i = 0; i < 2; ++i) {
                acc2[i] = __builtin_amdgcn_mfma_f32_16x16x32_bf16(wa2h[i][s + 2], f2h[s], acc2[i], 0, 0, 0);
                acc2[i] = __builtin_amdgcn_mfma_f32_16x16x32_bf16(wa2h[i][s + 2], f2l[s], acc2[i], 0, 0, 0);
                acc2[i] = __builtin_amdgcn_mfma_f32_16x16x32_bf16(wa2l[i][s + 2], f2h[s], acc2[i], 0, 0, 0);
            }

        // ---------- elementwise 2 -> hb2[p], h2f[p] ----------
#pragma unroll
        for (int i = 0; i < 2; ++i) if (tok[i]) {
            float cn = fmaf(sig_pre(acc2[i][1]), c2[i], sig_pre(acc2[i][0]) * tanh_pre(acc2[i][2]));
            c2[i] = cn;
            float h = sig_pre(acc2[i][3]) * tanh_pre(cn * TWOLOG2E);
            if (cok[i]) {
                int j = cellj[i];
                int s = j >> 5, q = (j & 31) >> 3, j7 = j & 7;
                unsigned short hi = bf16_rne(h);
                ((short*)&hb2[p][0][s][q * 16 + n])[j7] = (short)hi;
                ((short*)&hb2[p][1][s][q * 16 + n])[j7] = (short)bf16_rne(h - bf16f(hi));
                h2f[p][j * 16 + n] = h;
            }
        }
        // no trailing barrier: next iteration's barrier covers publication
    }

    // ---------- epilogue: y(2047) + final chunk flush ----------
    __syncthreads();   // h2f[1] (written at t=2047) visible
    if (wv == 7) {
        const int b = lane & 15, kg = lane >> 4;
        float a = 0.f;
#pragma unroll
        for (int it = 0; it < 13; ++it) {
            int j = kg + it * 4;
            if (j < H) a = fmaf(wlin[j], h2f[1][j * 16 + b], a);
        }
        a += __shfl_xor(a, 16, 64);
        a += __shfl_xor(a, 32, 64);
        if (kg == 0) ybf[b][63] = a + wlin[H];
#pragma unroll
        for (int r = 0; r < BB; ++r)
            out[(size_t)(b0 + r) * TSEQ + (TSEQ - 64) + lane] = ybf[r][lane];
    }
}

extern "C" void kernel_launch(void* const* d_in, const int* in_sizes, int n_in,
                              void* d_out, int out_size, void* d_ws, size_t ws_size,
                              hipStream_t stream) {
    const float* input = (const float*)d_in[0];
    const float* W_ih1 = (const float*)d_in[1];
    const float* W_hh1 = (const float*)d_in[2];
    const float* b_ih1 = (const float*)d_in[3];
    const float* b_hh1 = (const float*)d_in[4];
    const float* W_ih2 = (const float*)d_in[5];
    const float* W_hh2 = (const float*)d_in[6];
    const float* b_ih2 = (const float*)d_in[7];
    const float* b_hh2 = (const float*)d_in[8];
    const float* W_lin = (const float*)d_in[9];
    const float* b_lin = (const float*)d_in[10];

    lstm_mfma_kernel<<<dim3(2048 / BB), dim3(THREADS), 0, stream>>>(
        input, W_ih1, W_hh1, b_ih1, b_hh1,
        W_ih2, W_hh2, b_ih2, b_hh2, W_lin, b_lin,
        (float*)d_out);
}